// Round 19
// baseline (107.115 us; speedup 1.0000x reference)
//
#include <hip/hip_runtime.h>
#include <math.h>

#define B_      4
#define NH      8
#define HD      32
#define WINNUM  49
#define LWIN    3136
#define NTOK    3137
#define NPIX    12544     // B * 56 * 56
#define MROWS   12548     // NPIX + 4 cls rows
// 256^-0.5 * log2(e): scores land in exp2 domain (no bias: cancels in norm)
#define SCALE_L2E 0.09016844005556021f

typedef _Float16 half_t;
using half8  = __attribute__((ext_vector_type(8))) half_t;
using half4  = __attribute__((ext_vector_type(4))) half_t;
using f32x4  = __attribute__((ext_vector_type(4))) float;
using f32x16 = __attribute__((ext_vector_type(16))) float;

__device__ __forceinline__ float fexp2(float x) {
    return __builtin_amdgcn_exp2f(x);     // raw v_exp_f32 (1 ulp)
}
__device__ __forceinline__ unsigned pack2(float a, float b) {
    auto h = __builtin_amdgcn_cvt_pkrtz(a, b);
    return __builtin_bit_cast(unsigned, h);
}
__device__ __forceinline__ half8 as_h8(int4 v) {
    return __builtin_bit_cast(half8, v);
}
__device__ __forceinline__ unsigned short h2u(half_t h) {
    return __builtin_bit_cast(unsigned short, h);
}

// ---------------------------------------------------------------------------
// prep: weight conversions only. Wqkvt (768,256), Wot (256,256) transposed.
// ---------------------------------------------------------------------------
__global__ __launch_bounds__(256)
void prep(const float* __restrict__ Wqkv, const float* __restrict__ Wo,
          half_t* __restrict__ Wqkvt, half_t* __restrict__ Wot)
{
    const int idx = blockIdx.x * 256 + threadIdx.x;
    const int stride = gridDim.x * 256;
    for (int i = idx; i < 768 * 256; i += stride) {
        int n = i >> 8, k = i & 255;
        Wqkvt[i] = (half_t)Wqkv[k * 768 + n];
    }
    for (int i = idx; i < 256 * 256; i += stride) {
        int n = i >> 8, k = i & 255;
        Wot[i] = (half_t)Wo[k * 256 + n];
    }
}

// ---------------------------------------------------------------------------
// qkv_gemm: C = [x;cls] @ Wqkv + bqkv via fp16 MFMA, 128x256 tile, 8 waves
// (512 threads, 2x4). One block covers a full q/k/v part for its 128 rows
// -> A read 3x (was 6x). Epilogue: two 128-col phases through LDS, coalesced
// layout-native stores.
// ---------------------------------------------------------------------------
__global__ __launch_bounds__(512, 1)
void qkv_gemm(const float* __restrict__ x, const float* __restrict__ cls,
              const half_t* __restrict__ Bt, const float* __restrict__ bqkv,
              half_t* __restrict__ qh, half_t* __restrict__ kh,
              half_t* __restrict__ khcls, half_t* __restrict__ vh,
              half_t* __restrict__ vplain)
{
    __shared__ __align__(16) char smem[61440];
    short (*As)[128 * 40] = (short (*)[128 * 40])smem;            // 2 x 10240B
    short (*Bs)[256 * 40] = (short (*)[256 * 40])(smem + 20480);  // 2 x 20480B
    half_t* Cl = (half_t*)smem;                                   // [128][136]

    const int m0 = blockIdx.y * 128;
    const int part = blockIdx.x;            // 0=q 1=k 2=v
    const int n0 = part * 256;
    const int tid = threadIdx.x;
    const int lane = tid & 63, wv = tid >> 6;
    const int wm = wv >> 2, wn = wv & 3;
    const int qi = lane & 15, g = lane >> 4;
    f32x4 acc[4][4] = {};

    float4 rfa[2];
    int4 rb[2];
    auto issue = [&](int k0) {
        {
            int row = tid >> 2, kc = (tid & 3) * 8;
            int m = m0 + row;
            if (m < MROWS) {
                const float* src = ((m < NPIX) ? (x + (size_t)m * 256)
                                               : (cls + (size_t)(m - NPIX) * 256)) + k0 + kc;
                rfa[0] = *(const float4*)src;
                rfa[1] = *(const float4*)(src + 4);
            } else {
                rfa[0] = rfa[1] = make_float4(0.f, 0.f, 0.f, 0.f);
            }
        }
#pragma unroll
        for (int i = 0; i < 2; ++i) {
            int ch = tid + 512 * i;
            int row = ch >> 2, kc = (ch & 3) * 8;
            rb[i] = *(const int4*)(Bt + (size_t)(n0 + row) * 256 + k0 + kc);
        }
    };
    auto commit = [&](int bu) {
        {
            int row = tid >> 2, kc = (tid & 3) * 8;
            uint4 pa = make_uint4(pack2(rfa[0].x, rfa[0].y), pack2(rfa[0].z, rfa[0].w),
                                  pack2(rfa[1].x, rfa[1].y), pack2(rfa[1].z, rfa[1].w));
            *(uint4*)&As[bu][row * 40 + kc] = pa;
        }
#pragma unroll
        for (int i = 0; i < 2; ++i) {
            int ch = tid + 512 * i;
            int row = ch >> 2, kc = (ch & 3) * 8;
            *(int4*)&Bs[bu][row * 40 + kc] = rb[i];
        }
    };

    issue(0); commit(0);
    __syncthreads();
    int buf = 0;
    for (int s = 0; s < 8; ++s) {
        if (s < 7) issue((s + 1) * 32);
        half8 af[4], bf[4];
#pragma unroll
        for (int f = 0; f < 4; ++f) {
            af[f] = *(const half8*)&As[buf][(wm * 64 + f * 16 + qi) * 40 + g * 8];
            bf[f] = *(const half8*)&Bs[buf][(wn * 64 + f * 16 + qi) * 40 + g * 8];
        }
#pragma unroll
        for (int fm = 0; fm < 4; ++fm)
#pragma unroll
            for (int fn = 0; fn < 4; ++fn)
                acc[fm][fn] = __builtin_amdgcn_mfma_f32_16x16x32_f16(af[fm], bf[fn], acc[fm][fn], 0, 0, 0);
        if (s < 7) commit(buf ^ 1);
        __syncthreads();
        buf ^= 1;
    }

    float bq[4];
#pragma unroll
    for (int fn = 0; fn < 4; ++fn) bq[fn] = bqkv[n0 + wn * 64 + fn * 16 + qi];

    // ---- two 128-column phases through LDS ----
#pragma unroll
    for (int ph = 0; ph < 2; ++ph) {
        __syncthreads();   // previous phase read-out (or MFMA loop) done
        if ((wn >> 1) == ph) {
#pragma unroll
            for (int fm = 0; fm < 4; ++fm)
#pragma unroll
                for (int r = 0; r < 4; ++r) {
                    int rl = wm * 64 + fm * 16 + g * 4 + r;
#pragma unroll
                    for (int fn = 0; fn < 4; ++fn) {
                        float val = acc[fm][fn][r] + bq[fn];
                        if (part == 0) val *= SCALE_L2E;
                        Cl[rl * 136 + (wn & 1) * 64 + fn * 16 + qi] = (half_t)val;
                    }
                }
        }
        __syncthreads();

        if (part == 0 || part == 2) {
            half_t* base = (part == 0) ? qh : vplain;
            int row = tid >> 2, hd4 = tid & 3;
            int m = m0 + row;
            if (m < MROWS) {
                int b, tok;
                if (m < NPIX) {
                    b = m / LWIN;
                    int p = m - b * LWIN;
                    int hh = p / 56, ww = p - hh * 56;
                    tok = ((hh >> 3) * 7 + (ww >> 3)) * 64 + ((hh & 7) << 3) + (ww & 7);
                } else { b = m - NPIX; tok = LWIN; }
                size_t bh = (size_t)(b * NH + ph * 4 + hd4);
                const half_t* src = Cl + row * 136 + hd4 * 32;
                half_t* dst = base + (bh * NTOK + tok) * 32;
#pragma unroll
                for (int j = 0; j < 4; ++j)
                    *(int4*)(dst + j * 8) = *(const int4*)(src + j * 8);
            }
        }
        if (part == 1) {
            int row = tid >> 2, hd4 = tid & 3;
            int m = m0 + row;
            if (m < MROWS) {
                size_t bh;
                half_t* dst;
                if (m < NPIX) {
                    int b = m / LWIN;
                    int p = m - b * LWIN;
                    int hh = p / 56, ww = p - hh * 56;
                    int tok = ((hh >> 3) * 7 + (ww >> 3)) * 64 + ((hh & 7) << 3) + (ww & 7);
                    bh = (size_t)(b * NH + ph * 4 + hd4);
                    dst = kh + bh * (WINNUM * 2560) + (tok >> 6) * 2560 + (tok & 63) * 40;
                } else {
                    bh = (size_t)((m - NPIX) * NH + ph * 4 + hd4);
                    dst = khcls + bh * 32;
                }
                const half_t* src = Cl + row * 136 + hd4 * 32;
#pragma unroll
                for (int j = 0; j < 4; ++j)
                    *(int4*)(dst + j * 8) = *(const int4*)(src + j * 8);
            }
        }
        if (part == 2) {
#pragma unroll
            for (int c = 0; c < 4; ++c) {
                int ch = tid + 512 * c;
                int run = ch >> 7;           // 0..15
                int hd4 = (ch >> 5) & 3;
                int d   = ch & 31;
                int m = m0 + run * 8;
                if (m >= NPIX) continue;
                int b = m / LWIN;
                int p = m - b * LWIN;
                int hh = p / 56, ww = p - hh * 56;    // ww % 8 == 0
                int win = (hh >> 3) * 7 + (ww >> 3);
                int tokb = (hh & 7) << 3;
                const half_t* src = Cl + (run * 8) * 136 + hd4 * 32 + d;
                unsigned w0 = (unsigned)h2u(src[0])       | ((unsigned)h2u(src[136]) << 16);
                unsigned w1 = (unsigned)h2u(src[2 * 136]) | ((unsigned)h2u(src[3 * 136]) << 16);
                unsigned w2 = (unsigned)h2u(src[4 * 136]) | ((unsigned)h2u(src[5 * 136]) << 16);
                unsigned w3 = (unsigned)h2u(src[6 * 136]) | ((unsigned)h2u(src[7 * 136]) << 16);
                size_t bh = (size_t)(b * NH + ph * 4 + hd4);
                half_t* dst = vh + bh * (WINNUM * 2560) + win * 2560 + d * 80 + tokb;
                *(int4*)dst = make_int4(w0, w1, w2, w3);
            }
        }
    }
}

// ---------------------------------------------------------------------------
// win_attn (fused): ids [0,1568) window attention (barrier-free, 32x32x16
// MFMA, LDS P path, raw v_exp_f32 softmax); ids [1568,1824) cls partials;
// ids [1824,2608) lepe conv -> t2.
// ---------------------------------------------------------------------------
__global__ __launch_bounds__(128, 1)
void win_attn(const half_t* __restrict__ qh, const half_t* __restrict__ kh,
              const half_t* __restrict__ khcls, const half_t* __restrict__ vh,
              const half_t* __restrict__ vplain, const int* __restrict__ mask,
              const float* __restrict__ lk, const float* __restrict__ lb,
              half_t* __restrict__ tg, float* __restrict__ clspart,
              half_t* __restrict__ t2)
{
    const int id = blockIdx.x;
    const int tid = threadIdx.x;
    __shared__ __align__(16) short Plds[2][32 * 72];   // 9216 B
    __shared__ float redc[2 * 33];
    const int lane = tid & 63, wv = tid >> 6;

    if (id >= 1824) {
        // ---------------- lepe conv block -> t2 ----------------
        for (int task = (id - 1824) * 128 + tid; task < NPIX * 32; task += 784 * 128) {
            const int pix = task >> 5, cg = task & 31;
            const int c0 = cg * 8;
            const int b = pix / LWIN, p = pix - b * LWIN;
            const int hh = p / 56, ww = p - hh * 56;
            const int nh = c0 >> 5, d0 = c0 & 31;
            const half_t* vb = vplain + (size_t)(b * NH + nh) * NTOK * 32 + d0;
            float s[8];
#pragma unroll
            for (int j = 0; j < 8; ++j) s[j] = lb[c0 + j];
#pragma unroll
            for (int dh = -1; dh <= 1; ++dh) {
                int hn = hh + dh;
                if (hn < 0 || hn >= 56) continue;
#pragma unroll
                for (int dw = -1; dw <= 1; ++dw) {
                    int wn = ww + dw;
                    if (wn < 0 || wn >= 56) continue;
                    int tok = ((hn >> 3) * 7 + (wn >> 3)) * 64 + ((hn & 7) << 3) + (wn & 7);
                    half8 vvv = *(const half8*)(vb + (size_t)tok * 32);
                    const float* kk = lk + ((dh + 1) * 3 + (dw + 1)) * 256 + c0;
#pragma unroll
                    for (int j = 0; j < 8; ++j) s[j] += (float)vvv[j] * kk[j];
                }
            }
            half8 outv;
#pragma unroll
            for (int j = 0; j < 8; ++j) outv[j] = (half_t)s[j];
            *(half8*)(t2 + (size_t)pix * 256 + c0) = outv;
        }
        return;
    }

    if (id >= 1568) {
        // ---------------- cls partial block ----------------
        const int cid = id - 1568;
        const int bh = cid >> 3;
        const int chunk = cid & 7;
        const int wstart = chunk * 6;
        const int nw = (chunk < 7) ? 6 : 7;
        const int nkeys = nw * 64;

        float q[32];
        {
            const half_t* qp = qh + ((size_t)bh * NTOK + LWIN) * 32;
#pragma unroll
            for (int d = 0; d < 32; ++d) q[d] = (float)qp[d];
        }
        float l = 0.f, o[32];
#pragma unroll
        for (int d = 0; d < 32; ++d) o[d] = 0.f;

        const half_t* kwb = kh + (size_t)bh * (WINNUM * 2560) + wstart * 2560;
        const half_t* vb  = vplain + ((size_t)bh * NTOK + wstart * 64) * 32;

        for (int kk = tid; kk < nkeys; kk += 128) {
            const half_t* kp = kwb + (kk >> 6) * 2560 + (kk & 63) * 40;
            float s = 0.f;
#pragma unroll
            for (int c8 = 0; c8 < 4; ++c8) {
                half8 kv = *(const half8*)(kp + c8 * 8);
#pragma unroll
                for (int j = 0; j < 8; ++j) s += q[c8 * 8 + j] * (float)kv[j];
            }
            float pp = fexp2(s);
            l += pp;
            const half_t* vp = vb + (size_t)kk * 32;
#pragma unroll
            for (int c8 = 0; c8 < 4; ++c8) {
                half8 vvv = *(const half8*)(vp + c8 * 8);
#pragma unroll
                for (int j = 0; j < 8; ++j) o[c8 * 8 + j] += pp * (float)vvv[j];
            }
        }
        if (chunk == 7 && tid == 0) {    // cls key
            const half_t* kp = khcls + bh * 32;
            float s = 0.f;
#pragma unroll
            for (int d = 0; d < 32; ++d) s += q[d] * (float)kp[d];
            float pp = fexp2(s);
            l += pp;
            const half_t* vp = vplain + ((size_t)bh * NTOK + LWIN) * 32;
#pragma unroll
            for (int d = 0; d < 32; ++d) o[d] += pp * (float)vp[d];
        }
#pragma unroll
        for (int off = 1; off < 64; off <<= 1) {
            l += __shfl_xor(l, off);
#pragma unroll
            for (int d = 0; d < 32; ++d) o[d] += __shfl_xor(o[d], off);
        }
        if (lane == 0) {
#pragma unroll
            for (int d = 0; d < 32; ++d) redc[wv * 33 + d] = o[d];
            redc[wv * 33 + 32] = l;
        }
        __syncthreads();
        if (tid < 33) {
            clspart[(bh * 8 + chunk) * 33 + tid] = redc[tid] + redc[33 + tid];
        }
        return;
    }

    // ---------------- window-attention block (no barriers) ----------------
    const int sw = (id & 7) * 196 + (id >> 3);   // XCD-chunked swizzle
    const int wi = sw % 49;
    const int bh = sw / 49;
    const int b = bh >> 3, nh = bh & 7;

    const int qc = lane & 31;      // query col / A-row index
    const int hb = lane >> 5;      // k-group (0/1)
    const int qbase = wi * 64 + wv * 32;

    const half_t* qp = qh + ((size_t)bh * NTOK + qbase + qc) * 32 + hb * 8;
    half8 aq0 = as_h8(*(const int4*)(qp));
    half8 aq1 = as_h8(*(const int4*)(qp + 16));

    const f32x16 Z16 = {0.f,0.f,0.f,0.f,0.f,0.f,0.f,0.f,0.f,0.f,0.f,0.f,0.f,0.f,0.f,0.f};
    f32x16 acc = Z16;
    float lacc = 0.f;

    const int* mrow = mask + (b * WINNUM + wi) * WINNUM;
    int mv = (lane < WINNUM) ? mrow[lane] : 0;
    unsigned long long rem = __ballot(mv != 0);

    const half_t* kwin = kh + (size_t)bh * (WINNUM * 2560);
    const half_t* vwin = vh + (size_t)bh * (WINNUM * 2560);

    short* pw = &Plds[wv][qc * 72];
    const short* prd = &Plds[wv][qc * 72 + hb * 8];

    while (rem) {
        const int wj = __builtin_ctzll(rem);
        rem &= rem - 1;
        const half_t* kb = kwin + wj * 2560 + qc * 40 + hb * 8;
        const half_t* vb = vwin + wj * 2560 + qc * 80 + hb * 8;
        int4 kf00 = *(const int4*)(kb);
        int4 kf01 = *(const int4*)(kb + 16);
        int4 kf10 = *(const int4*)(kb + 1280);
        int4 kf11 = *(const int4*)(kb + 1296);
        int4 vf0 = *(const int4*)(vb);
        int4 vf1 = *(const int4*)(vb + 16);
        int4 vf2 = *(const int4*)(vb + 32);
        int4 vf3 = *(const int4*)(vb + 48);

        f32x16 st0, st1;
        __builtin_amdgcn_s_setprio(1);
        st0 = __builtin_amdgcn_mfma_f32_32x32x16_f16(as_h8(kf00), aq0, Z16, 0, 0, 0);
        st1 = __builtin_amdgcn_mfma_f32_32x32x16_f16(as_h8(kf10), aq0, Z16, 0, 0, 0);
        st0 = __builtin_amdgcn_mfma_f32_32x32x16_f16(as_h8(kf01), aq1, st0, 0, 0, 0);
        st1 = __builtin_amdgcn_mfma_f32_32x32x16_f16(as_h8(kf11), aq1, st1, 0, 0, 0);
        __builtin_amdgcn_s_setprio(0);

        // p = exp2(s) via raw v_exp_f32; accumulate l; pack to per-wave LDS
#pragma unroll
        for (int rb = 0; rb < 4; ++rb) {
            float p0 = fexp2(st0[4 * rb + 0]);
            float p1 = fexp2(st0[4 * rb + 1]);
            float p2 = fexp2(st0[4 * rb + 2]);
            float p3 = fexp2(st0[4 * rb + 3]);
            lacc += (p0 + p1) + (p2 + p3);
            *(uint2*)&pw[8 * rb + 4 * hb] = make_uint2(pack2(p0, p1), pack2(p2, p3));
        }
#pragma unroll
        for (int rb = 0; rb < 4; ++rb) {
            float p0 = fexp2(st1[4 * rb + 0]);
            float p1 = fexp2(st1[4 * rb + 1]);
            float p2 = fexp2(st1[4 * rb + 2]);
            float p3 = fexp2(st1[4 * rb + 3]);
            lacc += (p0 + p1) + (p2 + p3);
            *(uint2*)&pw[32 + 8 * rb + 4 * hb] = make_uint2(pack2(p0, p1), pack2(p2, p3));
        }
        half8 pB0 = *(const half8*)(prd);
        half8 pB1 = *(const half8*)(prd + 16);
        half8 pB2 = *(const half8*)(prd + 32);
        half8 pB3 = *(const half8*)(prd + 48);
        __builtin_amdgcn_s_setprio(1);
        acc = __builtin_amdgcn_mfma_f32_32x32x16_f16(as_h8(vf0), pB0, acc, 0, 0, 0);
        acc = __builtin_amdgcn_mfma_f32_32x32x16_f16(as_h8(vf1), pB1, acc, 0, 0, 0);
        acc = __builtin_amdgcn_mfma_f32_32x32x16_f16(as_h8(vf2), pB2, acc, 0, 0, 0);
        acc = __builtin_amdgcn_mfma_f32_32x32x16_f16(as_h8(vf3), pB3, acc, 0, 0, 0);
        __builtin_amdgcn_s_setprio(0);
    }

    // l[qc] = own 32 keys + partner's 32 keys (lanes qc and qc+32)
    lacc += __shfl_xor(lacc, 32);

    // cls key
    float sc = 0.f;
    {
        const half_t* kcb = khcls + bh * 32 + hb * 8;
        half8 kc0 = *(const half8*)(kcb);
        half8 kc1 = *(const half8*)(kcb + 16);
#pragma unroll
        for (int j = 0; j < 8; ++j)
            sc += (float)aq0[j] * (float)kc0[j] + (float)aq1[j] * (float)kc1[j];
        sc += __shfl_xor(sc, 32);
    }
    float pc = fexp2(sc);
    float l = lacc + pc;
    {
        const half_t* vcb = vplain + ((size_t)bh * NTOK + LWIN) * 32;
#pragma unroll
        for (int rb = 0; rb < 4; ++rb) {
            half4 vc = *(const half4*)(vcb + 8 * rb + 4 * hb);
#pragma unroll
            for (int r = 0; r < 4; ++r) acc[4 * rb + r] += pc * (float)vc[r];
        }
    }

    // write O/l: lane holds q=qc, d = 8rb + 4hb + r
    {
        float inv = 1.f / l;
        int kk = wv * 32 + qc;
        int hh = (wi / 7) * 8 + (kk >> 3);
        int ww = (wi % 7) * 8 + (kk & 7);
        size_t pix = (size_t)b * LWIN + hh * 56 + ww;
        half_t* tp = tg + pix * 256 + nh * 32;
#pragma unroll
        for (int rb = 0; rb < 4; ++rb) {
            half4 hv;
#pragma unroll
            for (int r = 0; r < 4; ++r) hv[r] = (half_t)(acc[4 * rb + r] * inv);
            *(half4*)(tp + 8 * rb + 4 * hb) = hv;
        }
    }
}

// ---------------------------------------------------------------------------
// out_gemm: out = (t + t2) @ Wo + bo (fp16 MFMA, fp32 out). 64x128 tile.
// cls rows (last row-tile) computed inline from clspart.
// ---------------------------------------------------------------------------
__global__ __launch_bounds__(256, 1)
void out_gemm(const half_t* __restrict__ th, const half_t* __restrict__ t2,
              const float* __restrict__ clspart,
              const half_t* __restrict__ Bt, const float* __restrict__ bo,
              float* __restrict__ out)
{
    __shared__ __align__(16) short As[2][64 * 40];
    __shared__ __align__(16) short Bs[2][128 * 40];
    const int m0 = blockIdx.y * 64, n0 = blockIdx.x * 128;
    const int tid = threadIdx.x;
    const int lane = tid & 63, wv = tid >> 6;
    const int wm = wv >> 1, wn = wv & 1;
    const int qi = lane & 15, g = lane >> 4;
    f32x4 acc[2][4] = {};

    int4 ra, rb[2];
    auto issue = [&](int k0) {
        {
            int row = tid >> 2, kc = (tid & 3) * 8;
            int m = m0 + row;
            if (m < NPIX) {
                half8 a = *(const half8*)(th + (size_t)m * 256 + k0 + kc);
                half8 b2 = *(const half8*)(t2 + (size_t)m * 256 + k0 + kc);
                half8 s = a + b2;
                ra = __builtin_bit_cast(int4, s);
            } else if (m < MROWS) {
                int bcls = m - NPIX;
                half_t tmp[8];
#pragma unroll
                for (int j = 0; j < 8; ++j) {
                    int c = k0 + kc + j;
                    int bh = bcls * NH + (c >> 5);
                    int d = c & 31;
                    float os = 0.f, ls = 0.f;
#pragma unroll
                    for (int ch = 0; ch < 8; ++ch) {
                        os += clspart[(bh * 8 + ch) * 33 + d];
                        ls += clspart[(bh * 8 + ch) * 33 + 32];
                    }
                    tmp[j] = (half_t)(os / ls);
                }
                ra = *(const int4*)tmp;
            } else {
                ra = make_int4(0, 0, 0, 0);
            }
        }
#pragma unroll
        for (int i = 0; i < 2; ++i) {
            int ch = tid + 256 * i;
            int row = ch >> 2, kc = (ch & 3) * 8;
            rb[i] = *(const int4*)(Bt + (size_t)(n0 + row) * 256 + k0 + kc);
        }
    };
    auto commit = [&](int bu) {
        {
            int row = tid >> 2, kc = (tid & 3) * 8;
            *(int4*)&As[bu][row * 40 + kc] = ra;
        }
#pragma unroll
        for (int i = 0; i < 2; ++i) {
            int ch = tid + 256 * i;
            int row = ch >> 2, kc = (ch & 3) * 8;
            *(int4*)&Bs[bu][row * 40 + kc] = rb[i];
        }
    };

    issue(0); commit(0);
    __syncthreads();
    int buf = 0;
    for (int s = 0; s < 8; ++s) {
        if (s < 7) issue((s + 1) * 32);
        half8 af[2], bf[4];
#pragma unroll
        for (int f = 0; f < 2; ++f)
            af[f] = *(const half8*)&As[buf][(wm * 32 + f * 16 + qi) * 40 + g * 8];
#pragma unroll
        for (int f = 0; f < 4; ++f)
            bf[f] = *(const half8*)&Bs[buf][(wn * 64 + f * 16 + qi) * 40 + g * 8];
#pragma unroll
        for (int fm = 0; fm < 2; ++fm)
#pragma unroll
            for (int fn = 0; fn < 4; ++fn)
                acc[fm][fn] = __builtin_amdgcn_mfma_f32_16x16x32_f16(af[fm], bf[fn], acc[fm][fn], 0, 0, 0);
        if (s < 7) commit(buf ^ 1);
        __syncthreads();
        buf ^= 1;
    }

    float bov[4];
    int nn[4];
#pragma unroll
    for (int fn = 0; fn < 4; ++fn) {
        nn[fn] = n0 + wn * 64 + fn * 16 + qi;
        bov[fn] = bo[nn[fn]];
    }
#pragma unroll
    for (int fm = 0; fm < 2; ++fm)
#pragma unroll
        for (int r = 0; r < 4; ++r) {
            int m = m0 + wm * 32 + fm * 16 + g * 4 + r;
            if (m >= MROWS) continue;
#pragma unroll
            for (int fn = 0; fn < 4; ++fn)
                out[(size_t)m * 256 + nn[fn]] = acc[fm][fn][r] + bov[fn];
        }
}

// ---------------------------------------------------------------------------
extern "C" void kernel_launch(void* const* d_in, const int* in_sizes, int n_in,
                              void* d_out, int out_size, void* d_ws, size_t ws_size,
                              hipStream_t stream)
{
    const float* x    = (const float*)d_in[0];
    const float* cls  = (const float*)d_in[1];
    const int*   mask = (const int*)d_in[2];
    const float* Wqkv = (const float*)d_in[5];
    const float* bqkv = (const float*)d_in[6];
    const float* Wo   = (const float*)d_in[7];
    const float* bo   = (const float*)d_in[8];
    const float* lk   = (const float*)d_in[9];
    const float* lb   = (const float*)d_in[10];
    float* out = (float*)d_out;

    char* w = (char*)d_ws;
    half_t* qh     = (half_t*)w;  w += 6424576;   // 32*3137*32*2
    half_t* kh     = (half_t*)w;  w += 8028160;   // 32*49*2560*2
    half_t* khcls  = (half_t*)w;  w += 2048;
    half_t* vh     = (half_t*)w;  w += 8028160;   // 32*49*2560*2 ([49][32][80])
    half_t* vplain = (half_t*)w;  w += 6424576;
    half_t* Wqkvt  = (half_t*)w;  w += 393216;
    half_t* Wot    = (half_t*)w;  w += 131072;
    half_t* th     = (half_t*)w;  w += 6424576;   // 12548*256*2
    half_t* t2     = (half_t*)w;  w += 6424576;   // NPIX*256*2 (lepe part)
    float*  clspart= (float*)w;   w += 33792;     // 32*8*33*4

    prep<<<256, 256, 0, stream>>>(Wqkv, Wo, Wqkvt, Wot);
    qkv_gemm<<<dim3(3, 99), 512, 0, stream>>>(x, cls, Wqkvt, bqkv, qh, kh, khcls, vh, vplain);
    win_attn<<<2608, 128, 0, stream>>>(qh, kh, khcls, vh, vplain, mask, lk, lb, th, clspart, t2);
    out_gemm<<<dim3(2, 197), 256, 0, stream>>>(th, t2, clspart, Wot, bo, out);
}

// Round 20
// 102.918 us; speedup vs baseline: 1.0408x; 1.0408x over previous
//
#include <hip/hip_runtime.h>
#include <math.h>

#define B_      4
#define NH      8
#define HD      32
#define WINNUM  49
#define LWIN    3136
#define NTOK    3137
#define NPIX    12544     // B * 56 * 56
#define MROWS   12548     // NPIX + 4 cls rows
// 256^-0.5 * log2(e): scores land in exp2 domain (no bias: cancels in norm)
#define SCALE_L2E 0.09016844005556021f

typedef _Float16 half_t;
using half8  = __attribute__((ext_vector_type(8))) half_t;
using half4  = __attribute__((ext_vector_type(4))) half_t;
using f32x4  = __attribute__((ext_vector_type(4))) float;
using f32x16 = __attribute__((ext_vector_type(16))) float;

__device__ __forceinline__ float fexp2(float x) {
    return __builtin_amdgcn_exp2f(x);     // raw v_exp_f32 (1 ulp)
}
__device__ __forceinline__ unsigned pack2(float a, float b) {
    auto h = __builtin_amdgcn_cvt_pkrtz(a, b);
    return __builtin_bit_cast(unsigned, h);
}
__device__ __forceinline__ half8 as_h8(int4 v) {
    return __builtin_bit_cast(half8, v);
}
__device__ __forceinline__ unsigned short h2u(half_t h) {
    return __builtin_bit_cast(unsigned short, h);
}

// ---------------------------------------------------------------------------
// prep: weight conversions only. Wqkvt (768,256), Wot (256,256) transposed.
// ---------------------------------------------------------------------------
__global__ __launch_bounds__(256)
void prep(const float* __restrict__ Wqkv, const float* __restrict__ Wo,
          half_t* __restrict__ Wqkvt, half_t* __restrict__ Wot)
{
    const int idx = blockIdx.x * 256 + threadIdx.x;
    const int stride = gridDim.x * 256;
    for (int i = idx; i < 768 * 256; i += stride) {
        int n = i >> 8, k = i & 255;
        Wqkvt[i] = (half_t)Wqkv[k * 768 + n];
    }
    for (int i = idx; i < 256 * 256; i += stride) {
        int n = i >> 8, k = i & 255;
        Wot[i] = (half_t)Wo[k * 256 + n];
    }
}

// ---------------------------------------------------------------------------
// qkv_gemm: C = [x;cls] @ Wqkv + bqkv via fp16 MFMA, 128x128 tile, 4 waves.
// A staged directly from fp32 with cvt_pkrtz in registers (reg-staged dbuf).
// Epilogue stages C tile in LDS, then emits layout-native coalesced stores.
// ---------------------------------------------------------------------------
__global__ __launch_bounds__(256, 1)
void qkv_gemm(const float* __restrict__ x, const float* __restrict__ cls,
              const half_t* __restrict__ Bt, const float* __restrict__ bqkv,
              half_t* __restrict__ qh, half_t* __restrict__ kh,
              half_t* __restrict__ khcls, half_t* __restrict__ vh,
              half_t* __restrict__ vplain)
{
    __shared__ __align__(16) char smem[40960];
    short (*As)[128 * 40] = (short (*)[128 * 40])smem;            // [2][5120]
    short (*Bs)[128 * 40] = (short (*)[128 * 40])(smem + 20480);  // [2][5120]
    half_t* Cl = (half_t*)smem;                                   // [128][136]

    const int m0 = blockIdx.y * 128, n0 = blockIdx.x * 128;
    const int tid = threadIdx.x;
    const int lane = tid & 63, wv = tid >> 6;
    const int wm = wv >> 1, wn = wv & 1;
    const int qi = lane & 15, g = lane >> 4;
    f32x4 acc[4][4] = {};

    float4 rfa[2][2];
    int4 rb[2];
    auto issue = [&](int k0) {
#pragma unroll
        for (int i = 0; i < 2; ++i) {
            int ch = tid + 256 * i;
            int row = ch >> 2, kc = (ch & 3) * 8;
            int m = m0 + row;
            if (m < MROWS) {
                const float* src = ((m < NPIX) ? (x + (size_t)m * 256)
                                               : (cls + (size_t)(m - NPIX) * 256)) + k0 + kc;
                rfa[i][0] = *(const float4*)src;
                rfa[i][1] = *(const float4*)(src + 4);
            } else {
                rfa[i][0] = rfa[i][1] = make_float4(0.f, 0.f, 0.f, 0.f);
            }
            rb[i] = *(const int4*)(Bt + (size_t)(n0 + row) * 256 + k0 + kc);
        }
    };
    auto commit = [&](int bu) {
#pragma unroll
        for (int i = 0; i < 2; ++i) {
            int ch = tid + 256 * i;
            int row = ch >> 2, kc = (ch & 3) * 8;
            uint4 pa = make_uint4(pack2(rfa[i][0].x, rfa[i][0].y), pack2(rfa[i][0].z, rfa[i][0].w),
                                  pack2(rfa[i][1].x, rfa[i][1].y), pack2(rfa[i][1].z, rfa[i][1].w));
            *(uint4*)&As[bu][row * 40 + kc] = pa;
            *(int4*)&Bs[bu][row * 40 + kc] = rb[i];
        }
    };

    issue(0); commit(0);
    __syncthreads();
    int buf = 0;
    for (int s = 0; s < 8; ++s) {
        if (s < 7) issue((s + 1) * 32);
        half8 af[4], bf[4];
#pragma unroll
        for (int f = 0; f < 4; ++f) {
            af[f] = *(const half8*)&As[buf][(wm * 64 + f * 16 + qi) * 40 + g * 8];
            bf[f] = *(const half8*)&Bs[buf][(wn * 64 + f * 16 + qi) * 40 + g * 8];
        }
#pragma unroll
        for (int fm = 0; fm < 4; ++fm)
#pragma unroll
            for (int fn = 0; fn < 4; ++fn)
                acc[fm][fn] = __builtin_amdgcn_mfma_f32_16x16x32_f16(af[fm], bf[fn], acc[fm][fn], 0, 0, 0);
        if (s < 7) commit(buf ^ 1);
        __syncthreads();
        buf ^= 1;
    }

    const int part = n0 >> 8;   // 0=q 1=k 2=v (tiles don't straddle parts)
    const int headbase = (n0 & 255) >> 5;   // 0 or 4

    // ---- stage C (+bias, +q-scale) into LDS [128][136] ----
    float bq[4];
#pragma unroll
    for (int fn = 0; fn < 4; ++fn) bq[fn] = bqkv[n0 + wn * 64 + fn * 16 + qi];
#pragma unroll
    for (int fm = 0; fm < 4; ++fm)
#pragma unroll
        for (int r = 0; r < 4; ++r) {
            int rl = wm * 64 + fm * 16 + g * 4 + r;
#pragma unroll
            for (int fn = 0; fn < 4; ++fn) {
                float val = acc[fm][fn][r] + bq[fn];
                if (part == 0) val *= SCALE_L2E;
                Cl[rl * 136 + wn * 64 + fn * 16 + qi] = (half_t)val;
            }
        }
    __syncthreads();

    // ---- coalesced read-out ----
    if (part == 0 || part == 2) {
        half_t* base = (part == 0) ? qh : vplain;
#pragma unroll
        for (int c = 0; c < 2; ++c) {
            int ch = tid + 256 * c;
            int row = ch >> 2, hd4 = ch & 3;
            int m = m0 + row;
            if (m >= MROWS) continue;
            int b, tok;
            if (m < NPIX) {
                b = m / LWIN;
                int p = m - b * LWIN;
                int hh = p / 56, ww = p - hh * 56;
                tok = ((hh >> 3) * 7 + (ww >> 3)) * 64 + ((hh & 7) << 3) + (ww & 7);
            } else { b = m - NPIX; tok = LWIN; }
            size_t bh = (size_t)(b * NH + headbase + hd4);
            const half_t* src = Cl + row * 136 + hd4 * 32;
            half_t* dst = base + (bh * NTOK + tok) * 32;
#pragma unroll
            for (int j = 0; j < 4; ++j)
                *(int4*)(dst + j * 8) = *(const int4*)(src + j * 8);
        }
    }
    if (part == 1) {
#pragma unroll
        for (int c = 0; c < 2; ++c) {
            int ch = tid + 256 * c;
            int row = ch >> 2, hd4 = ch & 3;
            int m = m0 + row;
            if (m >= MROWS) continue;
            size_t bh;
            half_t* dst;
            if (m < NPIX) {
                int b = m / LWIN;
                int p = m - b * LWIN;
                int hh = p / 56, ww = p - hh * 56;
                int tok = ((hh >> 3) * 7 + (ww >> 3)) * 64 + ((hh & 7) << 3) + (ww & 7);
                bh = (size_t)(b * NH + headbase + hd4);
                dst = kh + bh * (WINNUM * 2560) + (tok >> 6) * 2560 + (tok & 63) * 40;
            } else {
                bh = (size_t)((m - NPIX) * NH + headbase + hd4);
                dst = khcls + bh * 32;
            }
            const half_t* src = Cl + row * 136 + hd4 * 32;
#pragma unroll
            for (int j = 0; j < 4; ++j)
                *(int4*)(dst + j * 8) = *(const int4*)(src + j * 8);
        }
    }
    if (part == 2) {
#pragma unroll
        for (int c = 0; c < 8; ++c) {
            int ch = tid + 256 * c;
            int run = ch >> 7;
            int hd4 = (ch >> 5) & 3;
            int d   = ch & 31;
            int m = m0 + run * 8;
            if (m >= NPIX) continue;
            int b = m / LWIN;
            int p = m - b * LWIN;
            int hh = p / 56, ww = p - hh * 56;        // ww % 8 == 0
            int win = (hh >> 3) * 7 + (ww >> 3);
            int tokb = (hh & 7) << 3;
            const half_t* src = Cl + (run * 8) * 136 + hd4 * 32 + d;
            unsigned w0 = (unsigned)h2u(src[0])       | ((unsigned)h2u(src[136]) << 16);
            unsigned w1 = (unsigned)h2u(src[2 * 136]) | ((unsigned)h2u(src[3 * 136]) << 16);
            unsigned w2 = (unsigned)h2u(src[4 * 136]) | ((unsigned)h2u(src[5 * 136]) << 16);
            unsigned w3 = (unsigned)h2u(src[6 * 136]) | ((unsigned)h2u(src[7 * 136]) << 16);
            size_t bh = (size_t)(b * NH + headbase + hd4);
            half_t* dst = vh + bh * (WINNUM * 2560) + win * 2560 + d * 80 + tokb;
            *(int4*)dst = make_int4(w0, w1, w2, w3);
        }
    }
}

// ---------------------------------------------------------------------------
// win_attn (fused): ids [0,1568) window attention (barrier-free, 32x32x16
// MFMA, LDS P path, raw v_exp_f32 softmax); ids [1568,1824) cls partials;
// ids [1824,2608) lepe conv -> t2.
// ---------------------------------------------------------------------------
__global__ __launch_bounds__(128, 1)
void win_attn(const half_t* __restrict__ qh, const half_t* __restrict__ kh,
              const half_t* __restrict__ khcls, const half_t* __restrict__ vh,
              const half_t* __restrict__ vplain, const int* __restrict__ mask,
              const float* __restrict__ lk, const float* __restrict__ lb,
              half_t* __restrict__ tg, float* __restrict__ clspart,
              half_t* __restrict__ t2)
{
    const int id = blockIdx.x;
    const int tid = threadIdx.x;
    __shared__ __align__(16) short Plds[2][32 * 72];   // 9216 B
    __shared__ float redc[2 * 33];
    const int lane = tid & 63, wv = tid >> 6;

    if (id >= 1824) {
        // ---------------- lepe conv block -> t2 ----------------
        for (int task = (id - 1824) * 128 + tid; task < NPIX * 32; task += 784 * 128) {
            const int pix = task >> 5, cg = task & 31;
            const int c0 = cg * 8;
            const int b = pix / LWIN, p = pix - b * LWIN;
            const int hh = p / 56, ww = p - hh * 56;
            const int nh = c0 >> 5, d0 = c0 & 31;
            const half_t* vb = vplain + (size_t)(b * NH + nh) * NTOK * 32 + d0;
            float s[8];
#pragma unroll
            for (int j = 0; j < 8; ++j) s[j] = lb[c0 + j];
#pragma unroll
            for (int dh = -1; dh <= 1; ++dh) {
                int hn = hh + dh;
                if (hn < 0 || hn >= 56) continue;
#pragma unroll
                for (int dw = -1; dw <= 1; ++dw) {
                    int wn = ww + dw;
                    if (wn < 0 || wn >= 56) continue;
                    int tok = ((hn >> 3) * 7 + (wn >> 3)) * 64 + ((hn & 7) << 3) + (wn & 7);
                    half8 vvv = *(const half8*)(vb + (size_t)tok * 32);
                    const float* kk = lk + ((dh + 1) * 3 + (dw + 1)) * 256 + c0;
#pragma unroll
                    for (int j = 0; j < 8; ++j) s[j] += (float)vvv[j] * kk[j];
                }
            }
            half8 outv;
#pragma unroll
            for (int j = 0; j < 8; ++j) outv[j] = (half_t)s[j];
            *(half8*)(t2 + (size_t)pix * 256 + c0) = outv;
        }
        return;
    }

    if (id >= 1568) {
        // ---------------- cls partial block ----------------
        const int cid = id - 1568;
        const int bh = cid >> 3;
        const int chunk = cid & 7;
        const int wstart = chunk * 6;
        const int nw = (chunk < 7) ? 6 : 7;
        const int nkeys = nw * 64;

        float q[32];
        {
            const half_t* qp = qh + ((size_t)bh * NTOK + LWIN) * 32;
#pragma unroll
            for (int d = 0; d < 32; ++d) q[d] = (float)qp[d];
        }
        float l = 0.f, o[32];
#pragma unroll
        for (int d = 0; d < 32; ++d) o[d] = 0.f;

        const half_t* kwb = kh + (size_t)bh * (WINNUM * 2560) + wstart * 2560;
        const half_t* vb  = vplain + ((size_t)bh * NTOK + wstart * 64) * 32;

        for (int kk = tid; kk < nkeys; kk += 128) {
            const half_t* kp = kwb + (kk >> 6) * 2560 + (kk & 63) * 40;
            float s = 0.f;
#pragma unroll
            for (int c8 = 0; c8 < 4; ++c8) {
                half8 kv = *(const half8*)(kp + c8 * 8);
#pragma unroll
                for (int j = 0; j < 8; ++j) s += q[c8 * 8 + j] * (float)kv[j];
            }
            float pp = fexp2(s);
            l += pp;
            const half_t* vp = vb + (size_t)kk * 32;
#pragma unroll
            for (int c8 = 0; c8 < 4; ++c8) {
                half8 vvv = *(const half8*)(vp + c8 * 8);
#pragma unroll
                for (int j = 0; j < 8; ++j) o[c8 * 8 + j] += pp * (float)vvv[j];
            }
        }
        if (chunk == 7 && tid == 0) {    // cls key
            const half_t* kp = khcls + bh * 32;
            float s = 0.f;
#pragma unroll
            for (int d = 0; d < 32; ++d) s += q[d] * (float)kp[d];
            float pp = fexp2(s);
            l += pp;
            const half_t* vp = vplain + ((size_t)bh * NTOK + LWIN) * 32;
#pragma unroll
            for (int d = 0; d < 32; ++d) o[d] += pp * (float)vp[d];
        }
#pragma unroll
        for (int off = 1; off < 64; off <<= 1) {
            l += __shfl_xor(l, off);
#pragma unroll
            for (int d = 0; d < 32; ++d) o[d] += __shfl_xor(o[d], off);
        }
        if (lane == 0) {
#pragma unroll
            for (int d = 0; d < 32; ++d) redc[wv * 33 + d] = o[d];
            redc[wv * 33 + 32] = l;
        }
        __syncthreads();
        if (tid < 33) {
            clspart[(bh * 8 + chunk) * 33 + tid] = redc[tid] + redc[33 + tid];
        }
        return;
    }

    // ---------------- window-attention block (no barriers) ----------------
    const int sw = (id & 7) * 196 + (id >> 3);   // XCD-chunked swizzle
    const int wi = sw % 49;
    const int bh = sw / 49;
    const int b = bh >> 3, nh = bh & 7;

    const int qc = lane & 31;      // query col / A-row index
    const int hb = lane >> 5;      // k-group (0/1)
    const int qbase = wi * 64 + wv * 32;

    const half_t* qp = qh + ((size_t)bh * NTOK + qbase + qc) * 32 + hb * 8;
    half8 aq0 = as_h8(*(const int4*)(qp));
    half8 aq1 = as_h8(*(const int4*)(qp + 16));

    const f32x16 Z16 = {0.f,0.f,0.f,0.f,0.f,0.f,0.f,0.f,0.f,0.f,0.f,0.f,0.f,0.f,0.f,0.f};
    f32x16 acc = Z16;
    float lacc = 0.f;

    const int* mrow = mask + (b * WINNUM + wi) * WINNUM;
    int mv = (lane < WINNUM) ? mrow[lane] : 0;
    unsigned long long rem = __ballot(mv != 0);

    const half_t* kwin = kh + (size_t)bh * (WINNUM * 2560);
    const half_t* vwin = vh + (size_t)bh * (WINNUM * 2560);

    short* pw = &Plds[wv][qc * 72];
    const short* prd = &Plds[wv][qc * 72 + hb * 8];

    while (rem) {
        const int wj = __builtin_ctzll(rem);
        rem &= rem - 1;
        const half_t* kb = kwin + wj * 2560 + qc * 40 + hb * 8;
        const half_t* vb = vwin + wj * 2560 + qc * 80 + hb * 8;
        int4 kf00 = *(const int4*)(kb);
        int4 kf01 = *(const int4*)(kb + 16);
        int4 kf10 = *(const int4*)(kb + 1280);
        int4 kf11 = *(const int4*)(kb + 1296);
        int4 vf0 = *(const int4*)(vb);
        int4 vf1 = *(const int4*)(vb + 16);
        int4 vf2 = *(const int4*)(vb + 32);
        int4 vf3 = *(const int4*)(vb + 48);

        f32x16 st0, st1;
        __builtin_amdgcn_s_setprio(1);
        st0 = __builtin_amdgcn_mfma_f32_32x32x16_f16(as_h8(kf00), aq0, Z16, 0, 0, 0);
        st1 = __builtin_amdgcn_mfma_f32_32x32x16_f16(as_h8(kf10), aq0, Z16, 0, 0, 0);
        st0 = __builtin_amdgcn_mfma_f32_32x32x16_f16(as_h8(kf01), aq1, st0, 0, 0, 0);
        st1 = __builtin_amdgcn_mfma_f32_32x32x16_f16(as_h8(kf11), aq1, st1, 0, 0, 0);
        __builtin_amdgcn_s_setprio(0);

        // p = exp2(s) via raw v_exp_f32; accumulate l; pack to per-wave LDS
#pragma unroll
        for (int rb = 0; rb < 4; ++rb) {
            float p0 = fexp2(st0[4 * rb + 0]);
            float p1 = fexp2(st0[4 * rb + 1]);
            float p2 = fexp2(st0[4 * rb + 2]);
            float p3 = fexp2(st0[4 * rb + 3]);
            lacc += (p0 + p1) + (p2 + p3);
            *(uint2*)&pw[8 * rb + 4 * hb] = make_uint2(pack2(p0, p1), pack2(p2, p3));
        }
#pragma unroll
        for (int rb = 0; rb < 4; ++rb) {
            float p0 = fexp2(st1[4 * rb + 0]);
            float p1 = fexp2(st1[4 * rb + 1]);
            float p2 = fexp2(st1[4 * rb + 2]);
            float p3 = fexp2(st1[4 * rb + 3]);
            lacc += (p0 + p1) + (p2 + p3);
            *(uint2*)&pw[32 + 8 * rb + 4 * hb] = make_uint2(pack2(p0, p1), pack2(p2, p3));
        }
        half8 pB0 = *(const half8*)(prd);
        half8 pB1 = *(const half8*)(prd + 16);
        half8 pB2 = *(const half8*)(prd + 32);
        half8 pB3 = *(const half8*)(prd + 48);
        __builtin_amdgcn_s_setprio(1);
        acc = __builtin_amdgcn_mfma_f32_32x32x16_f16(as_h8(vf0), pB0, acc, 0, 0, 0);
        acc = __builtin_amdgcn_mfma_f32_32x32x16_f16(as_h8(vf1), pB1, acc, 0, 0, 0);
        acc = __builtin_amdgcn_mfma_f32_32x32x16_f16(as_h8(vf2), pB2, acc, 0, 0, 0);
        acc = __builtin_amdgcn_mfma_f32_32x32x16_f16(as_h8(vf3), pB3, acc, 0, 0, 0);
        __builtin_amdgcn_s_setprio(0);
    }

    // l[qc] = own 32 keys + partner's 32 keys (lanes qc and qc+32)
    lacc += __shfl_xor(lacc, 32);

    // cls key
    float sc = 0.f;
    {
        const half_t* kcb = khcls + bh * 32 + hb * 8;
        half8 kc0 = *(const half8*)(kcb);
        half8 kc1 = *(const half8*)(kcb + 16);
#pragma unroll
        for (int j = 0; j < 8; ++j)
            sc += (float)aq0[j] * (float)kc0[j] + (float)aq1[j] * (float)kc1[j];
        sc += __shfl_xor(sc, 32);
    }
    float pc = fexp2(sc);
    float l = lacc + pc;
    {
        const half_t* vcb = vplain + ((size_t)bh * NTOK + LWIN) * 32;
#pragma unroll
        for (int rb = 0; rb < 4; ++rb) {
            half4 vc = *(const half4*)(vcb + 8 * rb + 4 * hb);
#pragma unroll
            for (int r = 0; r < 4; ++r) acc[4 * rb + r] += pc * (float)vc[r];
        }
    }

    // write O/l: lane holds q=qc, d = 8rb + 4hb + r
    {
        float inv = 1.f / l;
        int kk = wv * 32 + qc;
        int hh = (wi / 7) * 8 + (kk >> 3);
        int ww = (wi % 7) * 8 + (kk & 7);
        size_t pix = (size_t)b * LWIN + hh * 56 + ww;
        half_t* tp = tg + pix * 256 + nh * 32;
#pragma unroll
        for (int rb = 0; rb < 4; ++rb) {
            half4 hv;
#pragma unroll
            for (int r = 0; r < 4; ++r) hv[r] = (half_t)(acc[4 * rb + r] * inv);
            *(half4*)(tp + 8 * rb + 4 * hb) = hv;
        }
    }
}

// ---------------------------------------------------------------------------
// out_gemm: out = (t + t2) @ Wo + bo (fp16 MFMA, fp32 out). 64x128 tile.
// cls rows (last row-tile) computed inline from clspart.
// ---------------------------------------------------------------------------
__global__ __launch_bounds__(256, 1)
void out_gemm(const half_t* __restrict__ th, const half_t* __restrict__ t2,
              const float* __restrict__ clspart,
              const half_t* __restrict__ Bt, const float* __restrict__ bo,
              float* __restrict__ out)
{
    __shared__ __align__(16) short As[2][64 * 40];
    __shared__ __align__(16) short Bs[2][128 * 40];
    const int m0 = blockIdx.y * 64, n0 = blockIdx.x * 128;
    const int tid = threadIdx.x;
    const int lane = tid & 63, wv = tid >> 6;
    const int wm = wv >> 1, wn = wv & 1;
    const int qi = lane & 15, g = lane >> 4;
    f32x4 acc[2][4] = {};

    int4 ra, rb[2];
    auto issue = [&](int k0) {
        {
            int row = tid >> 2, kc = (tid & 3) * 8;
            int m = m0 + row;
            if (m < NPIX) {
                half8 a = *(const half8*)(th + (size_t)m * 256 + k0 + kc);
                half8 b2 = *(const half8*)(t2 + (size_t)m * 256 + k0 + kc);
                half8 s = a + b2;
                ra = __builtin_bit_cast(int4, s);
            } else if (m < MROWS) {
                int bcls = m - NPIX;
                half_t tmp[8];
#pragma unroll
                for (int j = 0; j < 8; ++j) {
                    int c = k0 + kc + j;
                    int bh = bcls * NH + (c >> 5);
                    int d = c & 31;
                    float os = 0.f, ls = 0.f;
#pragma unroll
                    for (int ch = 0; ch < 8; ++ch) {
                        os += clspart[(bh * 8 + ch) * 33 + d];
                        ls += clspart[(bh * 8 + ch) * 33 + 32];
                    }
                    tmp[j] = (half_t)(os / ls);
                }
                ra = *(const int4*)tmp;
            } else {
                ra = make_int4(0, 0, 0, 0);
            }
        }
#pragma unroll
        for (int i = 0; i < 2; ++i) {
            int ch = tid + 256 * i;
            int row = ch >> 2, kc = (ch & 3) * 8;
            rb[i] = *(const int4*)(Bt + (size_t)(n0 + row) * 256 + k0 + kc);
        }
    };
    auto commit = [&](int bu) {
        {
            int row = tid >> 2, kc = (tid & 3) * 8;
            *(int4*)&As[bu][row * 40 + kc] = ra;
        }
#pragma unroll
        for (int i = 0; i < 2; ++i) {
            int ch = tid + 256 * i;
            int row = ch >> 2, kc = (ch & 3) * 8;
            *(int4*)&Bs[bu][row * 40 + kc] = rb[i];
        }
    };

    issue(0); commit(0);
    __syncthreads();
    int buf = 0;
    for (int s = 0; s < 8; ++s) {
        if (s < 7) issue((s + 1) * 32);
        half8 af[2], bf[4];
#pragma unroll
        for (int f = 0; f < 2; ++f)
            af[f] = *(const half8*)&As[buf][(wm * 32 + f * 16 + qi) * 40 + g * 8];
#pragma unroll
        for (int f = 0; f < 4; ++f)
            bf[f] = *(const half8*)&Bs[buf][(wn * 64 + f * 16 + qi) * 40 + g * 8];
#pragma unroll
        for (int fm = 0; fm < 2; ++fm)
#pragma unroll
            for (int fn = 0; fn < 4; ++fn)
                acc[fm][fn] = __builtin_amdgcn_mfma_f32_16x16x32_f16(af[fm], bf[fn], acc[fm][fn], 0, 0, 0);
        if (s < 7) commit(buf ^ 1);
        __syncthreads();
        buf ^= 1;
    }

    float bov[4];
    int nn[4];
#pragma unroll
    for (int fn = 0; fn < 4; ++fn) {
        nn[fn] = n0 + wn * 64 + fn * 16 + qi;
        bov[fn] = bo[nn[fn]];
    }
#pragma unroll
    for (int fm = 0; fm < 2; ++fm)
#pragma unroll
        for (int r = 0; r < 4; ++r) {
            int m = m0 + wm * 32 + fm * 16 + g * 4 + r;
            if (m >= MROWS) continue;
#pragma unroll
            for (int fn = 0; fn < 4; ++fn)
                out[(size_t)m * 256 + nn[fn]] = acc[fm][fn][r] + bov[fn];
        }
}

// ---------------------------------------------------------------------------
extern "C" void kernel_launch(void* const* d_in, const int* in_sizes, int n_in,
                              void* d_out, int out_size, void* d_ws, size_t ws_size,
                              hipStream_t stream)
{
    const float* x    = (const float*)d_in[0];
    const float* cls  = (const float*)d_in[1];
    const int*   mask = (const int*)d_in[2];
    const float* Wqkv = (const float*)d_in[5];
    const float* bqkv = (const float*)d_in[6];
    const float* Wo   = (const float*)d_in[7];
    const float* bo   = (const float*)d_in[8];
    const float* lk   = (const float*)d_in[9];
    const float* lb   = (const float*)d_in[10];
    float* out = (float*)d_out;

    char* w = (char*)d_ws;
    half_t* qh     = (half_t*)w;  w += 6424576;   // 32*3137*32*2
    half_t* kh     = (half_t*)w;  w += 8028160;   // 32*49*2560*2
    half_t* khcls  = (half_t*)w;  w += 2048;
    half_t* vh     = (half_t*)w;  w += 8028160;   // 32*49*2560*2 ([49][32][80])
    half_t* vplain = (half_t*)w;  w += 6424576;
    half_t* Wqkvt  = (half_t*)w;  w += 393216;
    half_t* Wot    = (half_t*)w;  w += 131072;
    half_t* th     = (half_t*)w;  w += 6424576;   // 12548*256*2
    half_t* t2     = (half_t*)w;  w += 6424576;   // NPIX*256*2 (lepe part)
    float*  clspart= (float*)w;   w += 33792;     // 32*8*33*4

    prep<<<256, 256, 0, stream>>>(Wqkv, Wo, Wqkvt, Wot);
    qkv_gemm<<<dim3(6, 99), 256, 0, stream>>>(x, cls, Wqkvt, bqkv, qh, kh, khcls, vh, vplain);
    win_attn<<<2608, 128, 0, stream>>>(qh, kh, khcls, vh, vplain, mask, lk, lb, th, clspart, t2);
    out_gemm<<<dim3(2, 197), 256, 0, stream>>>(th, t2, clspart, Wot, bo, out);
}